// Round 2
// baseline (1510.883 us; speedup 1.0000x reference)
//
#include <hip/hip_runtime.h>
#include <hip/hip_bf16.h>

#define VV 100000
#define EE 128
#define BB 2048
#define BM 128
#define BN 128
#define NWG (((VV + BN - 1) / BN) * (BB / BM))   // 782*16 = 12512, % 8 == 0

typedef __bf16 bf16x8 __attribute__((ext_vector_type(8)));
typedef float  f32x4  __attribute__((ext_vector_type(4)));

__device__ __forceinline__ unsigned short f2bf(float f) {
    union { float f; unsigned u; } x; x.f = f;
    unsigned r = x.u + 0x7fffu + ((x.u >> 16) & 1u);  // RNE
    return (unsigned short)(r >> 16);
}

__device__ __forceinline__ void gload_lds16(const void* g, void* l) {
    __builtin_amdgcn_global_load_lds(
        (const __attribute__((address_space(1))) void*)g,
        (__attribute__((address_space(3))) void*)l, 16, 0, 0);
}

// emb[b][e] = W_center[e][idx[b]] + b_center[e], stored as bf16 bits.
// Also zero the per-row sum-exp accumulators (ws is re-poisoned each call).
__global__ __launch_bounds__(256) void prep_kernel(
    const int* __restrict__ idx, const float* __restrict__ Wc,
    const float* __restrict__ bc, unsigned short* __restrict__ embB,
    float* __restrict__ s)
{
    int gid = blockIdx.x * 256 + threadIdx.x;   // 0 .. 2048*128-1
    int b = gid >> 7, e = gid & 127;
    float v = Wc[(size_t)e * VV + idx[b]] + bc[e];
    embB[gid] = f2bf(v);
    if (gid < BB) s[gid] = 0.0f;
}

// W_out f32 -> bf16 once per call (25.6 MB); lets gemm stage via global_load_lds.
__global__ __launch_bounds__(256) void wconv_kernel(
    const float* __restrict__ W, unsigned short* __restrict__ Wb)
{
    int gid = blockIdx.x * 256 + threadIdx.x;   // * 8 elems; 12.8M/8 = 1.6M threads
    const float4* src = (const float4*)W + (size_t)gid * 2;
    float4 w0 = src[0], w1 = src[1];
    int4 o;
    o.x = f2bf(w0.x) | (f2bf(w0.y) << 16);
    o.y = f2bf(w0.z) | (f2bf(w0.w) << 16);
    o.z = f2bf(w1.x) | (f2bf(w1.y) << 16);
    o.w = f2bf(w1.z) | (f2bf(w1.w) << 16);
    *(int4*)(Wb + (size_t)gid * 8) = o;
}

__global__ __launch_bounds__(256) void lse_kernel(
    const float* __restrict__ s, float* __restrict__ lse)
{
    int gid = blockIdx.x * 256 + threadIdx.x;
    if (gid < BB) lse[gid] = logf(s[gid]);
}

// 128x128 output tile; K=128, no K loop. A (emb) read per-fragment from global
// (512 KB, L2-resident). B (W_out) staged in LDS, bf16, XOR-swizzled
// (byte ^= (row&7)<<4 -> 2-way max on ds_read_b128), exactly 32 KB -> 5 blocks/CU.
// MFMA operands SWAPPED: D row = vocab, D col (l16) = batch. Each lane's 4 acc
// regs are 4 consecutive vocab cols -> float4 stores + float4 bout loads.
// PRE=1: W_out pre-converted to bf16, staged via global_load_lds w/ pre-swizzled
// source (linear LDS dest). PRE=0 fallback: in-kernel convert + swizzled ds_write.
// PASS 1: per-row sum(exp(logit)) -> global atomics. PASS 2: write log-softmax.
template <int PASS, int PRE>
__global__ __launch_bounds__(256, 5) void gemm_kernel(
    const unsigned short* __restrict__ embB,   // [B][128] bf16 bits
    const float*  __restrict__ Wout,           // [V][128] f32
    const unsigned short* __restrict__ WoutB,  // [V][128] bf16 bits (PRE=1)
    const float*  __restrict__ bout,           // [V]
    float* __restrict__ sumexp,                // [B]   (pass 1)
    const float* __restrict__ lse,             // [B]   (pass 2)
    float* __restrict__ out)                   // [B][V] (pass 2)
{
    __shared__ __align__(16) unsigned short sB[BN * 128];   // 32768 B exactly

    const int tid  = threadIdx.x;
    const int lane = tid & 63;
    const int wave = tid >> 6;

    // XCD-aware bijective remap (12512 = 8 * 1564)
    const int bid   = blockIdx.y * gridDim.x + blockIdx.x;
    const int wgid  = (bid & 7) * (NWG / 8) + (bid >> 3);
    const int rbase = (wgid & 15) * BM;        // 16 row tiles
    const int vbase = (wgid >> 4) * BN;        // 782 vocab tiles

    if (PRE) {
        // global_load_lds: wave-uniform LDS base + lane*16 (linear dest).
        // Source pre-swizzled so LDS element (row,k) lands at
        // row*256 + (2k ^ ((row&7)<<4)).
        const int lrow = lane >> 4;                 // 0..3
        const int lcol = (lane & 15) << 4;          // byte within row
        #pragma unroll
        for (int it = 0; it < 8; ++it) {
            int r  = it * 16 + wave * 4 + lrow;     // 0..127
            int vr = vbase + r; if (vr > VV - 1) vr = VV - 1;   // tail clamp
            const char* g = (const char*)WoutB + (size_t)vr * 256
                          + (lcol ^ ((r & 7) << 4));
            char* l = (char*)sB + (it * 16 + wave * 4) * 256;   // wave-uniform
            gload_lds16(g, l);
        }
    } else {
        #pragma unroll
        for (int it = 0; it < 16; ++it) {
            int k4 = tid + it * 256;               // 0..4095
            int row = k4 >> 5, c4 = k4 & 31;
            int v = vbase + row;
            float4 w = make_float4(0.f, 0.f, 0.f, 0.f);
            if (v < VV) w = *(const float4*)(Wout + (size_t)v * EE + c4 * 4);
            int2 h;
            h.x = f2bf(w.x) | (f2bf(w.y) << 16);
            h.y = f2bf(w.z) | (f2bf(w.w) << 16);
            *(int2*)((char*)sB + row * 256 + ((c4 * 8) ^ ((row & 7) << 4))) = h;
        }
    }
    __syncthreads();

    const int l16  = lane & 15;
    const int quad = lane >> 4;
    const int wr   = (wave >> 1) * 64;
    const int wc   = (wave & 1) * 64;

    f32x4 acc[4][4];
    #pragma unroll
    for (int i = 0; i < 4; ++i)
        #pragma unroll
        for (int j = 0; j < 4; ++j)
            acc[i][j] = (f32x4){0.f, 0.f, 0.f, 0.f};

    #pragma unroll
    for (int ks = 0; ks < 4; ++ks) {
        bf16x8 a[4], b[4];
        #pragma unroll
        for (int i = 0; i < 4; ++i)
            a[i] = *(const bf16x8*)(embB + (size_t)(rbase + wr + i * 16 + l16) * EE
                                         + ks * 32 + quad * 8);
        #pragma unroll
        for (int j = 0; j < 4; ++j) {
            int row = wc + j * 16 + l16;
            b[j] = *(const bf16x8*)((const char*)sB + row * 256
                                    + ((ks * 64 + quad * 16) ^ ((row & 7) << 4)));
        }
        // swapped: D = B_frag (vocab) x A_frag (batch) -> row=vocab, col=batch
        #pragma unroll
        for (int i = 0; i < 4; ++i)
            #pragma unroll
            for (int j = 0; j < 4; ++j)
                acc[i][j] = __builtin_amdgcn_mfma_f32_16x16x32_bf16(b[j], a[i], acc[i][j], 0, 0, 0);
    }

    // D layout: col = l16 -> batch m; row = quad*4 + r -> vocab v (4 consecutive)
    if (PASS == 1) {
        #pragma unroll
        for (int i = 0; i < 4; ++i) {
            float t = 0.f;
            #pragma unroll
            for (int j = 0; j < 4; ++j) {
                int v0 = vbase + wc + j * 16 + quad * 4;
                if (v0 < VV) {
                    float4 bo = *(const float4*)(bout + v0);
                    t += __expf(acc[i][j][0] + bo.x);
                    t += __expf(acc[i][j][1] + bo.y);
                    t += __expf(acc[i][j][2] + bo.z);
                    t += __expf(acc[i][j][3] + bo.w);
                }
            }
            t += __shfl_xor(t, 16);
            t += __shfl_xor(t, 32);
            if (lane < 16)
                atomicAdd(&sumexp[rbase + wr + i * 16 + lane], t);
        }
    } else {
        float l[4];
        #pragma unroll
        for (int i = 0; i < 4; ++i)
            l[i] = lse[rbase + wr + i * 16 + l16];
        #pragma unroll
        for (int j = 0; j < 4; ++j) {
            int v0 = vbase + wc + j * 16 + quad * 4;
            if (v0 < VV) {
                float4 bo = *(const float4*)(bout + v0);
                #pragma unroll
                for (int i = 0; i < 4; ++i) {
                    int m = rbase + wr + i * 16 + l16;
                    float4 st;
                    st.x = acc[i][j][0] + bo.x - l[i];
                    st.y = acc[i][j][1] + bo.y - l[i];
                    st.z = acc[i][j][2] + bo.z - l[i];
                    st.w = acc[i][j][3] + bo.w - l[i];
                    *(float4*)(out + (size_t)m * VV + v0) = st;
                }
            }
        }
    }
}

extern "C" void kernel_launch(void* const* d_in, const int* in_sizes, int n_in,
                              void* d_out, int out_size, void* d_ws, size_t ws_size,
                              hipStream_t stream) {
    const int*   idx  = (const int*)d_in[0];
    const float* Wc   = (const float*)d_in[1];
    const float* bc   = (const float*)d_in[2];
    const float* Wout = (const float*)d_in[3];
    const float* bout = (const float*)d_in[4];
    float* out = (float*)d_out;

    unsigned short* embB = (unsigned short*)d_ws;                 // 512 KB
    float* s   = (float*)((char*)d_ws + BB * EE * sizeof(unsigned short));
    float* lse = (float*)((char*)s + BB * sizeof(float));
    unsigned short* WoutB = (unsigned short*)((char*)lse + BB * sizeof(float));
    const size_t need = (size_t)BB * EE * 2 + 2 * BB * 4 + (size_t)VV * EE * 2;
    const bool pre = ws_size >= need;

    prep_kernel<<<(BB * EE) / 256, 256, 0, stream>>>(idx, Wc, bc, embB, s);
    if (pre)
        wconv_kernel<<<(VV * EE / 8) / 256, 256, 0, stream>>>(Wout, WoutB);

    dim3 grid(BB / BM, (VV + BN - 1) / BN);   // (16, 782)
    if (pre) {
        gemm_kernel<1, 1><<<grid, 256, 0, stream>>>(embB, Wout, WoutB, bout, s, nullptr, nullptr);
        lse_kernel<<<(BB + 255) / 256, 256, 0, stream>>>(s, lse);
        gemm_kernel<2, 1><<<grid, 256, 0, stream>>>(embB, Wout, WoutB, bout, nullptr, lse, out);
    } else {
        gemm_kernel<1, 0><<<grid, 256, 0, stream>>>(embB, Wout, WoutB, bout, s, nullptr, nullptr);
        lse_kernel<<<(BB + 255) / 256, 256, 0, stream>>>(s, lse);
        gemm_kernel<2, 0><<<grid, 256, 0, stream>>>(embB, Wout, WoutB, bout, nullptr, lse, out);
    }
}